// Round 15
// baseline (204.890 us; speedup 1.0000x reference)
//
#include <hip/hip_runtime.h>
#include <hip/hip_bf16.h>
#include <stdint.h>

// RelMHAtt: B=4 S=512 HIDDEN=1024 H=16 D=64 R=64
// MEASUREMENT ROUND: R14 split structure, but rel_kernel executes its work
// TWICE (identical values written twice -> deterministic). Purpose: push rel
// above the ~155us harness fill dispatches so its PMC row appears in top-5.
// True rel time = dur/2. Perf intentionally sacrificed this round.

typedef __attribute__((ext_vector_type(8))) short bf16x8;
typedef __attribute__((ext_vector_type(4))) float f32x4;

__device__ inline unsigned short f2bf(float f) {
    __hip_bfloat16 h = __float2bfloat16(f);
    return *reinterpret_cast<unsigned short*>(&h);
}
__device__ inline float bf2f(unsigned short u) {
    unsigned int t = ((unsigned int)u) << 16;
    return __builtin_bit_cast(float, t);
}

// ---------------------------------------------------------------- convert
// dst layout (bf16): xq[2M] xk[2M] xv[2M] Wq[1M] Wk[1M] Wv[1M] Wm[1M]
__global__ __launch_bounds__(256) void convert_kernel(
    const float* __restrict__ q, const float* __restrict__ k, const float* __restrict__ v,
    const float* __restrict__ wq, const float* __restrict__ wk, const float* __restrict__ wv,
    const float* __restrict__ wm, unsigned short* __restrict__ dst)
{
    const long long X = 2097152LL, Wn = 1048576LL;
    long long e = 4LL * ((long long)blockIdx.x * 256 + threadIdx.x);
    const float* s;
    long long o = e;
    if      (o < X)          { s = q; }
    else if (o < 2*X)        { s = k;  o -= X; }
    else if (o < 3*X)        { s = v;  o -= 2*X; }
    else if (o < 3*X + Wn)   { s = wq; o -= 3*X; }
    else if (o < 3*X + 2*Wn) { s = wk; o -= 3*X + Wn; }
    else if (o < 3*X + 3*Wn) { s = wv; o -= 3*X + 2*Wn; }
    else                     { s = wm; o -= 3*X + 3*Wn; }
    float4 val = *reinterpret_cast<const float4*>(s + o);
    ushort4 u;
    u.x = f2bf(val.x); u.y = f2bf(val.y); u.z = f2bf(val.z); u.w = f2bf(val.w);
    *reinterpret_cast<ushort4*>(dst + e) = u;
}

// ---------------------------------------------------------------- GEMM
// C[m,n] = sum_k A[m,k]*B[n,k] + bias[n];  BM=64, BN=128, BK=32; 4 waves.
// mode 0: f32 [M,1024]; 1: bf16 [M,1024]; 2: bf16*0.125; 3: bf16 vht[b][h][d][s]
struct GemmJob { const unsigned short* A; const unsigned short* B; const float* bias; char* C; int mode; };
struct Gemm3 { GemmJob j[3]; };

__global__ __launch_bounds__(256) void gemm_bt(Gemm3 g)
{
    GemmJob jb = g.j[blockIdx.z];
    const unsigned short* __restrict__ A = jb.A;
    const unsigned short* __restrict__ B = jb.B;
    __shared__ alignas(16) unsigned short As[2][2048];
    __shared__ alignas(16) unsigned short Bs[2][4096];
    int tid = threadIdx.x;
    int bm0 = blockIdx.x * 64, bn0 = blockIdx.y * 128;
    int wid = tid >> 6, lane = tid & 63;
    int fr = lane & 15, fq = lane >> 4;
    int wm = (wid >> 1) * 32, wn = (wid & 1) * 64;

    f32x4 acc[2][4];
    f32x4 z4 = {0.f, 0.f, 0.f, 0.f};
    for (int i = 0; i < 2; i++) for (int j = 0; j < 4; j++) acc[i][j] = z4;

    auto stage = [&](int buf, int kt) {
        {
            int ci = tid;
            int row = ci >> 2, kc = ci & 3;
            const unsigned short* ga = A + (long long)(bm0 + row) * 1024 + kt * 32 + kc * 8;
            __builtin_amdgcn_global_load_lds((const __attribute__((address_space(1))) void*)ga,
                (__attribute__((address_space(3))) void*)(&As[buf][ci * 8]), 16, 0, 0);
        }
        #pragma unroll
        for (int i = 0; i < 2; i++) {
            int ci = tid + 256 * i;
            int row = ci >> 2, kc = ci & 3;
            const unsigned short* gb = B + (long long)(bn0 + row) * 1024 + kt * 32 + kc * 8;
            __builtin_amdgcn_global_load_lds((const __attribute__((address_space(1))) void*)gb,
                (__attribute__((address_space(3))) void*)(&Bs[buf][ci * 8]), 16, 0, 0);
        }
    };
    auto compute = [&](int buf) {
        bf16x8 a[2], b[4];
        #pragma unroll
        for (int fm = 0; fm < 2; fm++)
            a[fm] = *reinterpret_cast<const bf16x8*>(&As[buf][(wm + fm*16 + fr)*32 + fq*8]);
        #pragma unroll
        for (int fn = 0; fn < 4; fn++)
            b[fn] = *reinterpret_cast<const bf16x8*>(&Bs[buf][(wn + fn*16 + fr)*32 + fq*8]);
        #pragma unroll
        for (int fm = 0; fm < 2; fm++)
            #pragma unroll
            for (int fn = 0; fn < 4; fn++)
                acc[fm][fn] = __builtin_amdgcn_mfma_f32_16x16x32_bf16(a[fm], b[fn], acc[fm][fn], 0, 0, 0);
    };

    stage(0, 0);
    asm volatile("s_waitcnt vmcnt(0)" ::: "memory");
    __syncthreads();
    int cur = 0;
    for (int kt = 0; kt < 31; kt++) {
        stage(cur ^ 1, kt + 1);
        compute(cur);
        asm volatile("s_waitcnt vmcnt(0)" ::: "memory");
        __syncthreads();
        cur ^= 1;
    }
    compute(cur);

    int mode = jb.mode;
    #pragma unroll
    for (int fm = 0; fm < 2; fm++) {
        #pragma unroll
        for (int fn = 0; fn < 4; fn++) {
            int col = bn0 + wn + fn*16 + fr;
            float bv = jb.bias[col];
            f32x4 vacc = acc[fm][fn];
            #pragma unroll
            for (int r = 0; r < 4; r++) {
                int m = bm0 + wm + fm*16 + fq*4 + r;
                float val = vacc[r] + bv;
                if (mode == 0) {
                    reinterpret_cast<float*>(jb.C)[(long long)m*1024 + col] = val;
                } else if (mode == 1) {
                    reinterpret_cast<unsigned short*>(jb.C)[(long long)m*1024 + col] = f2bf(val);
                } else if (mode == 2) {
                    reinterpret_cast<unsigned short*>(jb.C)[(long long)m*1024 + col] = f2bf(val * 0.125f);
                } else {
                    int bb = m >> 9, ss = m & 511;
                    int hh = col >> 6, dd = col & 63;
                    reinterpret_cast<unsigned short*>(jb.C)[(((long long)bb*16 + hh)*64 + dd)*512 + ss] = f2bf(val);
                }
            }
        }
    }
}

// ---------------------------------------------------------------- rel v10 x2 (measurement)
// biasW[b][q][kt][h][kl] = log(max(dot(rel[b,q,k,:], Wr[h,:]) + br[h], 1e-6)) bf16.
// Identical v10 body executed twice (rep loop) to exceed harness fill duration
// and surface this kernel's PMC row. True rel time = dur/2.
__global__ __launch_bounds__(256) void rel_kernel(
    const float* __restrict__ rel, const float* __restrict__ Wr,
    const float* __restrict__ br, unsigned short* __restrict__ biasW)
{
    __shared__ alignas(16) char relbuf[49152];
    int tid = threadIdx.x;
    int wid = tid >> 6, lane = tid & 63;
    int fr = lane & 15, fq = lane >> 4;
    char* wbase = relbuf + wid * 12288;

    bf16x8 whi[2], wlo[2];
    {
        const float* wp = Wr + fr*64 + fq*8;
        #pragma unroll
        for (int c = 0; c < 2; c++) {
            #pragma unroll
            for (int j = 0; j < 8; j++) {
                float w = wp[c*32 + j];
                unsigned int u = __builtin_bit_cast(unsigned int, w);
                float hi = __builtin_bit_cast(float, u & 0xffff0000u);
                float lo = w - hi;
                whi[c][j] = (short)(u >> 16);
                wlo[c][j] = (short)(__builtin_bit_cast(unsigned int, lo) >> 16);
            }
        }
    }
    float brv = br[fr];

    long long row0 = (long long)blockIdx.x * 512 + wid * 128;

    auto LOADT = [&](int t, int slot) {
        long long rtile = row0 + t*16;
        #pragma unroll
        for (int j = 0; j < 4; j++) {
            int rrow = j*4 + (lane >> 4);
            int scol = ((lane & 15) << 2) ^ ((rrow & 7) << 2);   // pre-swizzled source col
            const float* gsrc = rel + (rtile + rrow)*64 + scol;
            __builtin_amdgcn_global_load_lds(
                (const __attribute__((address_space(1))) void*)gsrc,
                (__attribute__((address_space(3))) void*)(wbase + slot*4096 + j*1024 + lane*16),
                16, 0, 0);
        }
    };

    int swz = (fr & 7) << 2;
    for (int rep = 0; rep < 2; ++rep) {
        asm volatile("s_waitcnt vmcnt(0)" ::: "memory");   // ledger = 0 at rep start
        LOADT(0, 0); LOADT(1, 1); LOADT(2, 2);             // 12 loads in flight

        #pragma unroll
        for (int t = 0; t < 8; t++) {
            // exact in-order ledger: loads=4 ops/tile, store=1 op/tile
            if      (t == 0) asm volatile("s_waitcnt vmcnt(8)"  ::: "memory");
            else if (t == 1) asm volatile("s_waitcnt vmcnt(9)"  ::: "memory");
            else if (t <= 5) asm volatile("s_waitcnt vmcnt(10)" ::: "memory");
            else if (t == 6) asm volatile("s_waitcnt vmcnt(6)"  ::: "memory");
            else             asm volatile("s_waitcnt vmcnt(2)"  ::: "memory");

            const int slot = t % 3;
            const char* sb = wbase + slot*4096 + fr*256;
            f32x4 x[4];
            x[0] = *reinterpret_cast<const f32x4*>(sb + (((fq*8     ) ^ swz) << 2));
            x[1] = *reinterpret_cast<const f32x4*>(sb + (((fq*8 +  4) ^ swz) << 2));
            x[2] = *reinterpret_cast<const f32x4*>(sb + (((fq*8 + 32) ^ swz) << 2));
            x[3] = *reinterpret_cast<const f32x4*>(sb + (((fq*8 + 36) ^ swz) << 2));

            bf16x8 ahi[2], alo[2];
            #pragma unroll
            for (int c = 0; c < 2; c++) {
                #pragma unroll
                for (int p = 0; p < 2; p++) {
                    f32x4 x4 = x[c*2 + p];
                    #pragma unroll
                    for (int e = 0; e < 4; e++) {
                        float xx = x4[e];
                        unsigned int u = __builtin_bit_cast(unsigned int, xx);
                        float hi = __builtin_bit_cast(float, u & 0xffff0000u);
                        float lo = xx - hi;                      // exact
                        ahi[c][p*4 + e] = (short)(u >> 16);
                        alo[c][p*4 + e] = (short)(__builtin_bit_cast(unsigned int, lo) >> 16);
                    }
                }
            }

            f32x4 acc = {0.f, 0.f, 0.f, 0.f};
            acc = __builtin_amdgcn_mfma_f32_16x16x32_bf16(ahi[0], whi[0], acc, 0, 0, 0);
            acc = __builtin_amdgcn_mfma_f32_16x16x32_bf16(ahi[1], whi[1], acc, 0, 0, 0);
            acc = __builtin_amdgcn_mfma_f32_16x16x32_bf16(alo[0], whi[0], acc, 0, 0, 0);
            acc = __builtin_amdgcn_mfma_f32_16x16x32_bf16(alo[1], whi[1], acc, 0, 0, 0);
            acc = __builtin_amdgcn_mfma_f32_16x16x32_bf16(ahi[0], wlo[0], acc, 0, 0, 0);
            acc = __builtin_amdgcn_mfma_f32_16x16x32_bf16(ahi[1], wlo[1], acc, 0, 0, 0);

            long long rtile = row0 + t*16;
            int b  = (int)(rtile >> 18);
            int q  = (int)((rtile >> 9) & 511);
            int k0 = (int)(rtile & 511);
            ushort4 u4;
            unsigned short* up = reinterpret_cast<unsigned short*>(&u4);
            #pragma unroll
            for (int j = 0; j < 4; j++) {
                float val = acc[j] + brv;
                up[j] = f2bf(__logf(fmaxf(val, 1e-6f)));
            }
            // biasW[b][q][kt][h][kl]: wave stores one contiguous 512B block
            *reinterpret_cast<ushort4*>(
                biasW + ((long long)(b*512 + q)*32 + (k0 >> 4))*256 + fr*16 + fq*4) = u4;

            if (t + 3 < 8) {
                asm volatile("s_waitcnt lgkmcnt(0)" ::: "memory");   // ds_reads done -> slot reusable
                LOADT(t + 3, slot);
            }
        }
    }
}

// ---------------------------------------------------------------- attention
__global__ __launch_bounds__(256) void attn_kernel(
    const unsigned short* __restrict__ qh, const unsigned short* __restrict__ kh,
    const unsigned short* __restrict__ vht, const unsigned short* __restrict__ biasW,
    const unsigned char* __restrict__ mask, unsigned short* __restrict__ atted)
{
    __shared__ alignas(16) unsigned short Pl[16][520];
    __shared__ float pmax[4][16];
    __shared__ float psum[4][16];
    int tid = threadIdx.x;
    int wid = tid >> 6, lane = tid & 63;
    int fr = lane & 15, fq = lane >> 4;
    int q0 = blockIdx.x * 16;
    int h = blockIdx.y, b = blockIdx.z;

    bf16x8 aq[2];
    #pragma unroll
    for (int df = 0; df < 2; df++)
        aq[df] = *reinterpret_cast<const bf16x8*>(
            qh + (long long)(b*512 + q0 + fr)*1024 + h*64 + df*32 + fq*8);

    f32x4 s[8];
    #pragma unroll
    for (int kt = 0; kt < 8; kt++) {
        int cb = wid*128 + kt*16;
        f32x4 a4 = {0.f,0.f,0.f,0.f};
        #pragma unroll
        for (int df = 0; df < 2; df++) {
            bf16x8 bk = *reinterpret_cast<const bf16x8*>(
                kh + (long long)(b*512 + cb + fr)*1024 + h*64 + df*32 + fq*8);
            a4 = __builtin_amdgcn_mfma_f32_16x16x32_bf16(aq[df], bk, a4, 0, 0, 0);
        }
        s[kt] = a4;
    }

    // biasW[b][q][kt16][h][kl]: idx = (b*512+q)*8192 + kt16*256 + h*16 + kl
    const unsigned short* bbase = biasW + (long long)(b*512 + q0)*8192 + h*16 + fr;
    #pragma unroll
    for (int kt = 0; kt < 8; kt++) {
        int col = wid*128 + kt*16 + fr;
        bool mk = mask[b*512 + col] != 0;
        #pragma unroll
        for (int r = 0; r < 4; r++) {
            float bias = bf2f(bbase[(long long)(fq*4 + r)*8192 + (wid*8 + kt)*256]);
            float val = s[kt][r] + bias;
            s[kt][r] = mk ? -1e9f : val;
        }
    }

    float rm[4];
    #pragma unroll
    for (int r = 0; r < 4; r++) {
        float m = s[0][r];
        #pragma unroll
        for (int kt = 1; kt < 8; kt++) m = fmaxf(m, s[kt][r]);
        #pragma unroll
        for (int x = 1; x < 16; x <<= 1) m = fmaxf(m, __shfl_xor(m, x, 64));
        rm[r] = m;
    }
    #pragma unroll
    for (int r = 0; r < 4; r++)
        if (fr == r) pmax[wid][fq*4 + r] = rm[r];
    __syncthreads();
    #pragma unroll
    for (int r = 0; r < 4; r++) {
        float m = pmax[0][fq*4 + r];
        m = fmaxf(m, pmax[1][fq*4 + r]);
        m = fmaxf(m, pmax[2][fq*4 + r]);
        m = fmaxf(m, pmax[3][fq*4 + r]);
        rm[r] = m;
    }

    float sum[4] = {0.f, 0.f, 0.f, 0.f};
    #pragma unroll
    for (int kt = 0; kt < 8; kt++) {
        int col = wid*128 + kt*16 + fr;
        #pragma unroll
        for (int r = 0; r < 4; r++) {
            float p = __expf(s[kt][r] - rm[r]);
            sum[r] += p;
            Pl[fq*4 + r][col] = f2bf(p);
        }
    }
    #pragma unroll
    for (int r = 0; r < 4; r++) {
        float sv = sum[r];
        #pragma unroll
        for (int x = 1; x < 16; x <<= 1) sv += __shfl_xor(sv, x, 64);
        sum[r] = sv;
    }
    #pragma unroll
    for (int r = 0; r < 4; r++)
        if (fr == r) psum[wid][fq*4 + r] = sum[r];
    __syncthreads();
    float sumr[4];
    #pragma unroll
    for (int r = 0; r < 4; r++)
        sumr[r] = psum[0][fq*4+r] + psum[1][fq*4+r] + psum[2][fq*4+r] + psum[3][fq*4+r];

    int d0 = wid * 16;
    f32x4 acco = {0.f,0.f,0.f,0.f};
    for (int c = 0; c < 16; c++) {
        bf16x8 pa = *reinterpret_cast<const bf16x8*>(&Pl[fr][c*32 + fq*8]);
        bf16x8 bv = *reinterpret_cast<const bf16x8*>(
            vht + ((long long)(b*16 + h)*64 + d0 + fr)*512 + c*32 + fq*8);
        acco = __builtin_amdgcn_mfma_f32_16x16x32_bf16(pa, bv, acco, 0, 0, 0);
    }
    #pragma unroll
    for (int r = 0; r < 4; r++) {
        float val = acco[r] / sumr[r];
        atted[(long long)(b*512 + q0 + fq*4 + r)*1024 + h*64 + d0 + fr] = f2bf(val);
    }
}

// ---------------------------------------------------------------- launch
extern "C" void kernel_launch(void* const* d_in, const int* in_sizes, int n_in,
                              void* d_out, int out_size, void* d_ws, size_t ws_size,
                              hipStream_t stream)
{
    const float* v    = (const float*)d_in[0];
    const float* k    = (const float*)d_in[1];
    const float* q    = (const float*)d_in[2];
    const unsigned char* mask = (const unsigned char*)d_in[3];
    const float* rel  = (const float*)d_in[4];
    const float* Wv   = (const float*)d_in[5];
    const float* bv   = (const float*)d_in[6];
    const float* Wk   = (const float*)d_in[7];
    const float* bk   = (const float*)d_in[8];
    const float* Wq   = (const float*)d_in[9];
    const float* bq   = (const float*)d_in[10];
    const float* Wr   = (const float*)d_in[11];
    const float* br   = (const float*)d_in[12];
    const float* Wm   = (const float*)d_in[13];
    const float* bm   = (const float*)d_in[14];

    const long long MB = 1 << 20;
    char* W = (char*)d_ws;
    unsigned short* xq    = (unsigned short*)(W + 0*MB);
    unsigned short* xk    = (unsigned short*)(W + 4*MB);
    unsigned short* xv    = (unsigned short*)(W + 8*MB);
    unsigned short* Wqb   = (unsigned short*)(W + 12*MB);
    unsigned short* Wkb   = (unsigned short*)(W + 14*MB);
    unsigned short* Wvb   = (unsigned short*)(W + 16*MB);
    unsigned short* Wmb   = (unsigned short*)(W + 18*MB);
    unsigned short* qhb   = (unsigned short*)(W + 20*MB);
    unsigned short* khb   = (unsigned short*)(W + 24*MB);
    unsigned short* vht   = (unsigned short*)(W + 28*MB);
    unsigned short* atted = (unsigned short*)(W + 32*MB);
    unsigned short* biasW = (unsigned short*)(W + 36*MB);  // 32 MB

    convert_kernel<<<10240, 256, 0, stream>>>(q, k, v, Wq, Wk, Wv, Wm, (unsigned short*)W);

    Gemm3 gp;
    gp.j[0] = { xq, Wqb, bq, (char*)qhb, 2 };
    gp.j[1] = { xk, Wkb, bk, (char*)khb, 1 };
    gp.j[2] = { xv, Wvb, bv, (char*)vht, 3 };
    gemm_bt<<<dim3(32, 8, 3), 256, 0, stream>>>(gp);

    rel_kernel<<<2048, 256, 0, stream>>>(rel, Wr, br, biasW);

    attn_kernel<<<dim3(32, 16, 4), 256, 0, stream>>>(qhb, khb, vht, biasW, mask, atted);

    Gemm3 gf;
    gf.j[0] = { atted, Wmb, bm, (char*)d_out, 0 };
    gf.j[1] = gf.j[0];
    gf.j[2] = gf.j[0];
    gemm_bt<<<dim3(32, 8, 1), 256, 0, stream>>>(gf);
}

// Round 16
// 153.489 us; speedup vs baseline: 1.3349x; 1.3349x over previous
//
#include <hip/hip_runtime.h>
#include <hip/hip_bf16.h>
#include <stdint.h>

// RelMHAtt: B=4 S=512 HIDDEN=1024 H=16 D=64 R=64
// R13 fused structure + GEMM regime fix: BM=64/BN=64/BK=64, 4 waves x 32x32,
// XOR-swizzled LDS (both-sides, rule #21), 16 K-iters (half the drains),
// proj 1536 blocks / final 512 blocks (2x block-level overlap).
// R15 finding: rel v10 is already at HBM floor (~45us); proj GEMM was the pig
// (~60-90us, m102 small-N regime + 8-way LDS conflicts in old 32-col layout).

typedef __attribute__((ext_vector_type(8))) short bf16x8;
typedef __attribute__((ext_vector_type(4))) float f32x4;

__device__ inline unsigned short f2bf(float f) {
    __hip_bfloat16 h = __float2bfloat16(f);
    return *reinterpret_cast<unsigned short*>(&h);
}
__device__ inline float bf2f(unsigned short u) {
    unsigned int t = ((unsigned int)u) << 16;
    return __builtin_bit_cast(float, t);
}

// ---------------------------------------------------------------- convert
// dst layout (bf16): xq[2M] xk[2M] xv[2M] Wq[1M] Wk[1M] Wv[1M] Wm[1M]
__global__ __launch_bounds__(256) void convert_kernel(
    const float* __restrict__ q, const float* __restrict__ k, const float* __restrict__ v,
    const float* __restrict__ wq, const float* __restrict__ wk, const float* __restrict__ wv,
    const float* __restrict__ wm, unsigned short* __restrict__ dst)
{
    const long long X = 2097152LL, Wn = 1048576LL;
    long long e = 4LL * ((long long)blockIdx.x * 256 + threadIdx.x);
    const float* s;
    long long o = e;
    if      (o < X)          { s = q; }
    else if (o < 2*X)        { s = k;  o -= X; }
    else if (o < 3*X)        { s = v;  o -= 2*X; }
    else if (o < 3*X + Wn)   { s = wq; o -= 3*X; }
    else if (o < 3*X + 2*Wn) { s = wk; o -= 3*X + Wn; }
    else if (o < 3*X + 3*Wn) { s = wv; o -= 3*X + 2*Wn; }
    else                     { s = wm; o -= 3*X + 3*Wn; }
    float4 val = *reinterpret_cast<const float4*>(s + o);
    ushort4 u;
    u.x = f2bf(val.x); u.y = f2bf(val.y); u.z = f2bf(val.z); u.w = f2bf(val.w);
    *reinterpret_cast<ushort4*>(dst + e) = u;
}

// ---------------------------------------------------------------- GEMM defs
// C[m,n] = sum_k A[m,k]*B[n,k] + bias[n]; BM=BN=BK=64; 4 waves each 32x32.
// mode 0: f32 [M,1024]; 1: bf16 [M,1024]; 2: bf16*0.125; 3: bf16 vht[b][h][d][s]
struct GemmJob { const unsigned short* A; const unsigned short* B; const float* bias; char* C; int mode; };
struct Gemm3 { GemmJob j[3]; };

#define GEMM64_BODY(As, Bs, A, B, biasp, Cp, mode, bm0, bn0)                           \
    {                                                                                   \
        int wm = (wid >> 1) * 32, wn = (wid & 1) * 32;                                  \
        f32x4 acc[2][2];                                                                \
        f32x4 z4 = {0.f, 0.f, 0.f, 0.f};                                                \
        for (int i = 0; i < 2; i++) for (int j = 0; j < 2; j++) acc[i][j] = z4;         \
        auto stage = [&](int buf, int kt) {                                             \
            _Pragma("unroll")                                                           \
            for (int i = 0; i < 2; i++) {                                               \
                int ci = tid + 256 * i;                                                 \
                int row = ci >> 3, ch = ci & 7;                                         \
                int sch = ch ^ (row & 7);                                               \
                const unsigned short* ga = A + (long long)(bm0 + row) * 1024 + kt * 64 + sch * 8; \
                __builtin_amdgcn_global_load_lds((const __attribute__((address_space(1))) void*)ga, \
                    (__attribute__((address_space(3))) void*)(&As[buf][ci * 8]), 16, 0, 0); \
                const unsigned short* gb = B + (long long)(bn0 + row) * 1024 + kt * 64 + sch * 8; \
                __builtin_amdgcn_global_load_lds((const __attribute__((address_space(1))) void*)gb, \
                    (__attribute__((address_space(3))) void*)(&Bs[buf][ci * 8]), 16, 0, 0); \
            }                                                                           \
        };                                                                              \
        int rx = fr & 7;                                                                \
        auto compute = [&](int buf) {                                                   \
            _Pragma("unroll")                                                           \
            for (int ks = 0; ks < 2; ks++) {                                            \
                bf16x8 a[2], b[2];                                                      \
                _Pragma("unroll")                                                       \
                for (int fm = 0; fm < 2; fm++)                                          \
                    a[fm] = *reinterpret_cast<const bf16x8*>(                            \
                        &As[buf][(wm + fm*16 + fr)*64 + ((ks*4 + fq) ^ rx)*8]);          \
                _Pragma("unroll")                                                       \
                for (int fn = 0; fn < 2; fn++)                                          \
                    b[fn] = *reinterpret_cast<const bf16x8*>(                            \
                        &Bs[buf][(wn + fn*16 + fr)*64 + ((ks*4 + fq) ^ rx)*8]);          \
                _Pragma("unroll")                                                       \
                for (int fm = 0; fm < 2; fm++)                                          \
                    _Pragma("unroll")                                                   \
                    for (int fn = 0; fn < 2; fn++)                                      \
                        acc[fm][fn] = __builtin_amdgcn_mfma_f32_16x16x32_bf16(a[fm], b[fn], acc[fm][fn], 0, 0, 0); \
            }                                                                           \
        };                                                                              \
        stage(0, 0);                                                                    \
        asm volatile("s_waitcnt vmcnt(0)" ::: "memory");                                \
        __syncthreads();                                                                \
        int cur = 0;                                                                    \
        for (int kt = 0; kt < 15; kt++) {                                               \
            stage(cur ^ 1, kt + 1);                                                     \
            compute(cur);                                                               \
            asm volatile("s_waitcnt vmcnt(0)" ::: "memory");                            \
            __syncthreads();                                                            \
            cur ^= 1;                                                                   \
        }                                                                               \
        compute(cur);                                                                   \
        _Pragma("unroll")                                                               \
        for (int fm = 0; fm < 2; fm++) {                                                \
            _Pragma("unroll")                                                           \
            for (int fn = 0; fn < 2; fn++) {                                            \
                int col = bn0 + wn + fn*16 + fr;                                        \
                float bv = biasp[col];                                                  \
                f32x4 vacc = acc[fm][fn];                                               \
                _Pragma("unroll")                                                       \
                for (int r = 0; r < 4; r++) {                                           \
                    int m = bm0 + wm + fm*16 + fq*4 + r;                                \
                    float val = vacc[r] + bv;                                           \
                    if (mode == 0) {                                                    \
                        reinterpret_cast<float*>(Cp)[(long long)m*1024 + col] = val;    \
                    } else if (mode == 1) {                                             \
                        reinterpret_cast<unsigned short*>(Cp)[(long long)m*1024 + col] = f2bf(val); \
                    } else if (mode == 2) {                                             \
                        reinterpret_cast<unsigned short*>(Cp)[(long long)m*1024 + col] = f2bf(val * 0.125f); \
                    } else {                                                            \
                        int bb = m >> 9, ss = m & 511;                                  \
                        int hh = col >> 6, dd = col & 63;                               \
                        reinterpret_cast<unsigned short*>(Cp)[(((long long)bb*16 + hh)*64 + dd)*512 + ss] = f2bf(val); \
                    }                                                                   \
                }                                                                       \
            }                                                                           \
        }                                                                               \
    }

// ---------------------------------------------------------------- fused proj GEMM + rel v10
// blocks [0,1536): proj GEMM (job = bid>>9, m = (bid>>4)&31, n = bid&15)
// blocks [1536, 1536+2048): rel v10 (LDS-ring, counted vmcnt, coalesced biasW)
__global__ __launch_bounds__(256) void gemm_rel(
    Gemm3 g, const float* __restrict__ rel, const float* __restrict__ Wr,
    const float* __restrict__ br, unsigned short* __restrict__ biasW)
{
    __shared__ alignas(16) union SM {
        struct { unsigned short As[2][4096]; unsigned short Bs[2][4096]; } gm;  // 32 KB
        char relbuf[49152];                                                      // 48 KB
    } sm;
    int tid = threadIdx.x;
    int wid = tid >> 6, lane = tid & 63;
    int fr = lane & 15, fq = lane >> 4;

    if (blockIdx.x < 1536) {
        int bid = blockIdx.x;
        GemmJob jb = g.j[bid >> 9];
        const unsigned short* __restrict__ A = jb.A;
        const unsigned short* __restrict__ B = jb.B;
        int bm0 = ((bid >> 4) & 31) * 64, bn0 = (bid & 15) * 64;
        const float* biasp = jb.bias;
        char* Cp = jb.C;
        int mode = jb.mode;
        GEMM64_BODY(sm.gm.As, sm.gm.Bs, A, B, biasp, Cp, mode, bm0, bn0)
    } else {
        // ---------------- rel v10 role ----------------
        char* wbase = sm.relbuf + wid * 12288;

        bf16x8 whi[2], wlo[2];
        {
            const float* wp = Wr + fr*64 + fq*8;
            #pragma unroll
            for (int c = 0; c < 2; c++) {
                #pragma unroll
                for (int j = 0; j < 8; j++) {
                    float w = wp[c*32 + j];
                    unsigned int u = __builtin_bit_cast(unsigned int, w);
                    float hi = __builtin_bit_cast(float, u & 0xffff0000u);
                    float lo = w - hi;
                    whi[c][j] = (short)(u >> 16);
                    wlo[c][j] = (short)(__builtin_bit_cast(unsigned int, lo) >> 16);
                }
            }
        }
        float brv = br[fr];
        asm volatile("s_waitcnt vmcnt(0)" ::: "memory");   // ledger = 0

        long long row0 = (long long)(blockIdx.x - 1536) * 512 + wid * 128;

        auto LOADT = [&](int t, int slot) {
            long long rtile = row0 + t*16;
            #pragma unroll
            for (int j = 0; j < 4; j++) {
                int rrow = j*4 + (lane >> 4);
                int scol = ((lane & 15) << 2) ^ ((rrow & 7) << 2);
                const float* gsrc = rel + (rtile + rrow)*64 + scol;
                __builtin_amdgcn_global_load_lds(
                    (const __attribute__((address_space(1))) void*)gsrc,
                    (__attribute__((address_space(3))) void*)(wbase + slot*4096 + j*1024 + lane*16),
                    16, 0, 0);
            }
        };
        LOADT(0, 0); LOADT(1, 1); LOADT(2, 2);

        int swz = (fr & 7) << 2;
        #pragma unroll
        for (int t = 0; t < 8; t++) {
            if      (t == 0) asm volatile("s_waitcnt vmcnt(8)"  ::: "memory");
            else if (t == 1) asm volatile("s_waitcnt vmcnt(9)"  ::: "memory");
            else if (t <= 5) asm volatile("s_waitcnt vmcnt(10)" ::: "memory");
            else if (t == 6) asm volatile("s_waitcnt vmcnt(6)"  ::: "memory");
            else             asm volatile("s_waitcnt vmcnt(2)"  ::: "memory");

            const int slot = t % 3;
            const char* sb = wbase + slot*4096 + fr*256;
            f32x4 x[4];
            x[0] = *reinterpret_cast<const f32x4*>(sb + (((fq*8     ) ^ swz) << 2));
            x[1] = *reinterpret_cast<const f32x4*>(sb + (((fq*8 +  4) ^ swz) << 2));
            x[2] = *reinterpret_cast<const f32x4*>(sb + (((fq*8 + 32) ^ swz) << 2));
            x[3] = *reinterpret_cast<const f32x4*>(sb + (((fq*8 + 36) ^ swz) << 2));

            bf16x8 ahi[2], alo[2];
            #pragma unroll
            for (int c = 0; c < 2; c++) {
                #pragma unroll
                for (int p = 0; p < 2; p++) {
                    f32x4 x4 = x[c*2 + p];
                    #pragma unroll
                    for (int e = 0; e < 4; e++) {
                        float xx = x4[e];
                        unsigned int u = __builtin_bit_cast(unsigned int, xx);
                        float hi = __builtin_bit_cast(float, u & 0xffff0000u);
                        float lo = xx - hi;
                        ahi[c][p*4 + e] = (short)(u >> 16);
                        alo[c][p*4 + e] = (short)(__builtin_bit_cast(unsigned int, lo) >> 16);
                    }
                }
            }

            f32x4 acc = {0.f, 0.f, 0.f, 0.f};
            acc = __builtin_amdgcn_mfma_f32_16x16x32_bf16(ahi[0], whi[0], acc, 0, 0, 0);
            acc = __builtin_amdgcn_mfma_f32_16x16x32_bf16(ahi[1], whi[1], acc, 0, 0, 0);
            acc = __builtin_amdgcn_mfma_f32_16x16x32_bf16(alo[0], whi[0], acc, 0, 0, 0);
            acc = __builtin_amdgcn_mfma_f32_16x16x32_bf16(alo[1], whi[1], acc, 0, 0, 0);
            acc = __builtin_amdgcn_mfma_f32_16x16x32_bf16(ahi[0], wlo[0], acc, 0, 0, 0);
            acc = __builtin_amdgcn_mfma_f32_16x16x32_bf16(ahi[1], wlo[1], acc, 0, 0, 0);

            long long rtile = row0 + t*16;
            int b  = (int)(rtile >> 18);
            int q  = (int)((rtile >> 9) & 511);
            int k0 = (int)(rtile & 511);
            ushort4 u4;
            unsigned short* up = reinterpret_cast<unsigned short*>(&u4);
            #pragma unroll
            for (int j = 0; j < 4; j++) {
                float val = acc[j] + brv;
                up[j] = f2bf(__logf(fmaxf(val, 1e-6f)));
            }
            *reinterpret_cast<ushort4*>(
                biasW + ((long long)(b*512 + q)*32 + (k0 >> 4))*256 + fr*16 + fq*4) = u4;

            if (t + 3 < 8) {
                asm volatile("s_waitcnt lgkmcnt(0)" ::: "memory");
                LOADT(t + 3, slot);
            }
        }
    }
}

// ---------------------------------------------------------------- final GEMM (BM=BN=BK=64)
__global__ __launch_bounds__(256) void final_gemm(
    const unsigned short* __restrict__ A, const unsigned short* __restrict__ B,
    const float* __restrict__ bias, float* __restrict__ C)
{
    __shared__ alignas(16) unsigned short As[2][4096];
    __shared__ alignas(16) unsigned short Bs[2][4096];
    int tid = threadIdx.x;
    int wid = tid >> 6, lane = tid & 63;
    int fr = lane & 15, fq = lane >> 4;
    int bm0 = blockIdx.x * 64, bn0 = blockIdx.y * 64;
    const float* biasp = bias;
    char* Cp = (char*)C;
    const int mode = 0;
    GEMM64_BODY(As, Bs, A, B, biasp, Cp, mode, bm0, bn0)
}

// ---------------------------------------------------------------- attention
__global__ __launch_bounds__(256) void attn_kernel(
    const unsigned short* __restrict__ qh, const unsigned short* __restrict__ kh,
    const unsigned short* __restrict__ vht, const unsigned short* __restrict__ biasW,
    const unsigned char* __restrict__ mask, unsigned short* __restrict__ atted)
{
    __shared__ alignas(16) unsigned short Pl[16][520];
    __shared__ float pmax[4][16];
    __shared__ float psum[4][16];
    int tid = threadIdx.x;
    int wid = tid >> 6, lane = tid & 63;
    int fr = lane & 15, fq = lane >> 4;
    int q0 = blockIdx.x * 16;
    int h = blockIdx.y, b = blockIdx.z;

    bf16x8 aq[2];
    #pragma unroll
    for (int df = 0; df < 2; df++)
        aq[df] = *reinterpret_cast<const bf16x8*>(
            qh + (long long)(b*512 + q0 + fr)*1024 + h*64 + df*32 + fq*8);

    f32x4 s[8];
    #pragma unroll
    for (int kt = 0; kt < 8; kt++) {
        int cb = wid*128 + kt*16;
        f32x4 a4 = {0.f,0.f,0.f,0.f};
        #pragma unroll
        for (int df = 0; df < 2; df++) {
            bf16x8 bk = *reinterpret_cast<const bf16x8*>(
                kh + (long long)(b*512 + cb + fr)*1024 + h*64 + df*32 + fq*8);
            a4 = __builtin_amdgcn_mfma_f32_16x16x32_bf16(aq[df], bk, a4, 0, 0, 0);
        }
        s[kt] = a4;
    }

    // biasW[b][q][kt16][h][kl]: idx = (b*512+q)*8192 + kt16*256 + h*16 + kl
    const unsigned short* bbase = biasW + (long long)(b*512 + q0)*8192 + h*16 + fr;
    #pragma unroll
    for (int kt = 0; kt < 8; kt++) {
        int col = wid*128 + kt*16 + fr;
        bool mk = mask[b*512 + col] != 0;
        #pragma unroll
        for (int r = 0; r < 4; r++) {
            float bias = bf2f(bbase[(long long)(fq*4 + r)*8192 + (wid*8 + kt)*256]);
            float val = s[kt][r] + bias;
            s[kt][r] = mk ? -1e9f : val;
        }
    }

    float rm[4];
    #pragma unroll
    for (int r = 0; r < 4; r++) {
        float m = s[0][r];
        #pragma unroll
        for (int kt = 1; kt < 8; kt++) m = fmaxf(m, s[kt][r]);
        #pragma unroll
        for (int x = 1; x < 16; x <<= 1) m = fmaxf(m, __shfl_xor(m, x, 64));
        rm[r] = m;
    }
    #pragma unroll
    for (int r = 0; r < 4; r++)
        if (fr == r) pmax[wid][fq*4 + r] = rm[r];
    __syncthreads();
    #pragma unroll
    for (int r = 0; r < 4; r++) {
        float m = pmax[0][fq*4 + r];
        m = fmaxf(m, pmax[1][fq*4 + r]);
        m = fmaxf(m, pmax[2][fq*4 + r]);
        m = fmaxf(m, pmax[3][fq*4 + r]);
        rm[r] = m;
    }

    float sum[4] = {0.f, 0.f, 0.f, 0.f};
    #pragma unroll
    for (int kt = 0; kt < 8; kt++) {
        int col = wid*128 + kt*16 + fr;
        #pragma unroll
        for (int r = 0; r < 4; r++) {
            float p = __expf(s[kt][r] - rm[r]);
            sum[r] += p;
            Pl[fq*4 + r][col] = f2bf(p);
        }
    }
    #pragma unroll
    for (int r = 0; r < 4; r++) {
        float sv = sum[r];
        #pragma unroll
        for (int x = 1; x < 16; x <<= 1) sv += __shfl_xor(sv, x, 64);
        sum[r] = sv;
    }
    #pragma unroll
    for (int r = 0; r < 4; r++)
        if (fr == r) psum[wid][fq*4 + r] = sum[r];
    __syncthreads();
    float sumr[4];
    #pragma unroll
    for (int r = 0; r < 4; r++)
        sumr[r] = psum[0][fq*4+r] + psum[1][fq*4+r] + psum[2][fq*4+r] + psum[3][fq*4+r];

    int d0 = wid * 16;
    f32x4 acco = {0.f,0.f,0.f,0.f};
    for (int c = 0; c < 16; c++) {
        bf16x8 pa = *reinterpret_cast<const bf16x8*>(&Pl[fr][c*32 + fq*8]);
        bf16x8 bv = *reinterpret_cast<const bf16x8*>(
            vht + ((long long)(b*16 + h)*64 + d0 + fr)*512 + c*32 + fq*8);
        acco = __builtin_amdgcn_mfma_f32_16x16x32_bf16(pa, bv, acco, 0, 0, 0);
    }
    #pragma unroll
    for (int r = 0; r < 4; r++) {
        float val = acco[r] / sumr[r];
        atted[(long long)(b*512 + q0 + fq*4 + r)*1024 + h*64 + d0 + fr] = f2bf(val);
    }
}

// ---------------------------------------------------------------- launch
extern "C" void kernel_launch(void* const* d_in, const int* in_sizes, int n_in,
                              void* d_out, int out_size, void* d_ws, size_t ws_size,
                              hipStream_t stream)
{
    const float* v    = (const float*)d_in[0];
    const float* k    = (const float*)d_in[1];
    const float* q    = (const float*)d_in[2];
    const unsigned char* mask = (const unsigned char*)d_in[3];
    const float* rel  = (const float*)d_in[4];
    const float* Wv   = (const float*)d_in[5];
    const float* bv   = (const float*)d_in[6];
    const float* Wk   = (const float*)d_in[7];
    const float* bk   = (const float*)d_in[8];
    const float* Wq   = (const float*)d_in[9];
    const float* bq   = (const float*)d_in[10];
    const float* Wr   = (const float*)d_in[11];
    const float* br   = (const float*)d_in[12];
    const float* Wm   = (const float*)d_in[13];
    const float* bm   = (const float*)d_in[14];

    const long long MB = 1 << 20;
    char* W = (char*)d_ws;
    unsigned short* xq    = (unsigned short*)(W + 0*MB);
    unsigned short* xk    = (unsigned short*)(W + 4*MB);
    unsigned short* xv    = (unsigned short*)(W + 8*MB);
    unsigned short* Wqb   = (unsigned short*)(W + 12*MB);
    unsigned short* Wkb   = (unsigned short*)(W + 14*MB);
    unsigned short* Wvb   = (unsigned short*)(W + 16*MB);
    unsigned short* Wmb   = (unsigned short*)(W + 18*MB);
    unsigned short* qhb   = (unsigned short*)(W + 20*MB);
    unsigned short* khb   = (unsigned short*)(W + 24*MB);
    unsigned short* vht   = (unsigned short*)(W + 28*MB);
    unsigned short* atted = (unsigned short*)(W + 32*MB);
    unsigned short* biasW = (unsigned short*)(W + 36*MB);  // 32 MB

    convert_kernel<<<10240, 256, 0, stream>>>(q, k, v, Wq, Wk, Wv, Wm, (unsigned short*)W);

    Gemm3 gp;
    gp.j[0] = { xq, Wqb, bq, (char*)qhb, 2 };
    gp.j[1] = { xk, Wkb, bk, (char*)khb, 1 };
    gp.j[2] = { xv, Wvb, bv, (char*)vht, 3 };
    gemm_rel<<<1536 + 2048, 256, 0, stream>>>(gp, rel, Wr, br, biasW);

    attn_kernel<<<dim3(32, 16, 4), 256, 0, stream>>>(qhb, khb, vht, biasW, mask, atted);

    final_gemm<<<dim3(32, 16), 256, 0, stream>>>(atted, Wmb, bm, (float*)d_out);
}

// Round 17
// 142.712 us; speedup vs baseline: 1.4357x; 1.0755x over previous
//
#include <hip/hip_runtime.h>
#include <hip/hip_bf16.h>
#include <stdint.h>

// RelMHAtt: B=4 S=512 HIDDEN=1024 H=16 D=64 R=64
// R16 lesson: 64^2 tiles doubled operand traffic (~390MB) and 1536 GEMM blocks
// serialized ahead of rel. R17: proj back to m97 128x128xBK32 (874-TF ladder
// structure), only 384 blocks -> rel co-resident from t=0 (768 slots @ 3/CU).
// rel v10 (HBM-floor, R15-verified) unchanged. final 64^2 GEMM kept.

typedef __attribute__((ext_vector_type(8))) short bf16x8;
typedef __attribute__((ext_vector_type(4))) float f32x4;

__device__ inline unsigned short f2bf(float f) {
    __hip_bfloat16 h = __float2bfloat16(f);
    return *reinterpret_cast<unsigned short*>(&h);
}
__device__ inline float bf2f(unsigned short u) {
    unsigned int t = ((unsigned int)u) << 16;
    return __builtin_bit_cast(float, t);
}

// ---------------------------------------------------------------- convert
// dst layout (bf16): xq[2M] xk[2M] xv[2M] Wq[1M] Wk[1M] Wv[1M] Wm[1M]
__global__ __launch_bounds__(256) void convert_kernel(
    const float* __restrict__ q, const float* __restrict__ k, const float* __restrict__ v,
    const float* __restrict__ wq, const float* __restrict__ wk, const float* __restrict__ wv,
    const float* __restrict__ wm, unsigned short* __restrict__ dst)
{
    const long long X = 2097152LL, Wn = 1048576LL;
    long long e = 4LL * ((long long)blockIdx.x * 256 + threadIdx.x);
    const float* s;
    long long o = e;
    if      (o < X)          { s = q; }
    else if (o < 2*X)        { s = k;  o -= X; }
    else if (o < 3*X)        { s = v;  o -= 2*X; }
    else if (o < 3*X + Wn)   { s = wq; o -= 3*X; }
    else if (o < 3*X + 2*Wn) { s = wk; o -= 3*X + Wn; }
    else if (o < 3*X + 3*Wn) { s = wv; o -= 3*X + 2*Wn; }
    else                     { s = wm; o -= 3*X + 3*Wn; }
    float4 val = *reinterpret_cast<const float4*>(s + o);
    ushort4 u;
    u.x = f2bf(val.x); u.y = f2bf(val.y); u.z = f2bf(val.z); u.w = f2bf(val.w);
    *reinterpret_cast<ushort4*>(dst + e) = u;
}

// ---------------------------------------------------------------- GEMM defs
struct GemmJob { const unsigned short* A; const unsigned short* B; const float* bias; char* C; int mode; };
struct Gemm3 { GemmJob j[3]; };

// ---------------------------------------------------------------- fused proj GEMM (m97 128x128) + rel v10
// blocks [0,384): proj GEMM (job = bid>>7, m = (bid>>3)&15, n = bid&7)
// blocks [384, 384+2048): rel v10 (LDS-ring, counted vmcnt, coalesced biasW)
__global__ __launch_bounds__(256) void gemm_rel(
    Gemm3 g, const float* __restrict__ rel, const float* __restrict__ Wr,
    const float* __restrict__ br, unsigned short* __restrict__ biasW)
{
    __shared__ alignas(16) union SM {
        struct { unsigned short As[2][4096]; unsigned short Bs[2][4096]; } gm;  // 32 KB
        char relbuf[49152];                                                      // 48 KB
    } sm;
    int tid = threadIdx.x;
    int wid = tid >> 6, lane = tid & 63;
    int fr = lane & 15, fq = lane >> 4;

    if (blockIdx.x < 384) {
        // ---------------- proj GEMM role: m97 structure ----------------
        int bid = blockIdx.x;
        GemmJob jb = g.j[bid >> 7];
        const unsigned short* __restrict__ A = jb.A;
        const unsigned short* __restrict__ B = jb.B;
        int bm0 = ((bid >> 3) & 15) * 128, bn0 = (bid & 7) * 128;
        int wm = (wid >> 1) * 64, wn = (wid & 1) * 64;

        f32x4 acc[4][4];
        f32x4 z4 = {0.f, 0.f, 0.f, 0.f};
        for (int i = 0; i < 4; i++) for (int j = 0; j < 4; j++) acc[i][j] = z4;

        auto stage = [&](int buf, int kt) {
            #pragma unroll
            for (int i = 0; i < 2; i++) {
                int ci = tid + 256 * i;
                int row = ci >> 2, kc = ci & 3;
                const unsigned short* ga = A + (long long)(bm0 + row) * 1024 + kt * 32 + kc * 8;
                __builtin_amdgcn_global_load_lds((const __attribute__((address_space(1))) void*)ga,
                    (__attribute__((address_space(3))) void*)(&sm.gm.As[buf][ci * 8]), 16, 0, 0);
                const unsigned short* gb = B + (long long)(bn0 + row) * 1024 + kt * 32 + kc * 8;
                __builtin_amdgcn_global_load_lds((const __attribute__((address_space(1))) void*)gb,
                    (__attribute__((address_space(3))) void*)(&sm.gm.Bs[buf][ci * 8]), 16, 0, 0);
            }
        };
        auto compute = [&](int buf) {
            bf16x8 a[4], b[4];
            #pragma unroll
            for (int fm = 0; fm < 4; fm++)
                a[fm] = *reinterpret_cast<const bf16x8*>(&sm.gm.As[buf][(wm + fm*16 + fr)*32 + fq*8]);
            #pragma unroll
            for (int fn = 0; fn < 4; fn++)
                b[fn] = *reinterpret_cast<const bf16x8*>(&sm.gm.Bs[buf][(wn + fn*16 + fr)*32 + fq*8]);
            #pragma unroll
            for (int fm = 0; fm < 4; fm++)
                #pragma unroll
                for (int fn = 0; fn < 4; fn++)
                    acc[fm][fn] = __builtin_amdgcn_mfma_f32_16x16x32_bf16(a[fm], b[fn], acc[fm][fn], 0, 0, 0);
        };

        stage(0, 0);
        asm volatile("s_waitcnt vmcnt(0)" ::: "memory");
        __syncthreads();
        int cur = 0;
        for (int kt = 0; kt < 31; kt++) {
            stage(cur ^ 1, kt + 1);
            compute(cur);
            asm volatile("s_waitcnt vmcnt(0)" ::: "memory");
            __syncthreads();
            cur ^= 1;
        }
        compute(cur);

        int mode = jb.mode;
        #pragma unroll
        for (int fm = 0; fm < 4; fm++) {
            #pragma unroll
            for (int fn = 0; fn < 4; fn++) {
                int col = bn0 + wn + fn*16 + fr;
                float bv = jb.bias[col];
                f32x4 vacc = acc[fm][fn];
                #pragma unroll
                for (int r = 0; r < 4; r++) {
                    int m = bm0 + wm + fm*16 + fq*4 + r;
                    float val = vacc[r] + bv;
                    if (mode == 1) {
                        reinterpret_cast<unsigned short*>(jb.C)[(long long)m*1024 + col] = f2bf(val);
                    } else if (mode == 2) {
                        reinterpret_cast<unsigned short*>(jb.C)[(long long)m*1024 + col] = f2bf(val * 0.125f);
                    } else {
                        int bb = m >> 9, ss = m & 511;
                        int hh = col >> 6, dd = col & 63;
                        reinterpret_cast<unsigned short*>(jb.C)[(((long long)bb*16 + hh)*64 + dd)*512 + ss] = f2bf(val);
                    }
                }
            }
        }
    } else {
        // ---------------- rel v10 role ----------------
        char* wbase = sm.relbuf + wid * 12288;

        bf16x8 whi[2], wlo[2];
        {
            const float* wp = Wr + fr*64 + fq*8;
            #pragma unroll
            for (int c = 0; c < 2; c++) {
                #pragma unroll
                for (int j = 0; j < 8; j++) {
                    float w = wp[c*32 + j];
                    unsigned int u = __builtin_bit_cast(unsigned int, w);
                    float hi = __builtin_bit_cast(float, u & 0xffff0000u);
                    float lo = w - hi;
                    whi[c][j] = (short)(u >> 16);
                    wlo[c][j] = (short)(__builtin_bit_cast(unsigned int, lo) >> 16);
                }
            }
        }
        float brv = br[fr];
        asm volatile("s_waitcnt vmcnt(0)" ::: "memory");   // ledger = 0

        long long row0 = (long long)(blockIdx.x - 384) * 512 + wid * 128;

        auto LOADT = [&](int t, int slot) {
            long long rtile = row0 + t*16;
            #pragma unroll
            for (int j = 0; j < 4; j++) {
                int rrow = j*4 + (lane >> 4);
                int scol = ((lane & 15) << 2) ^ ((rrow & 7) << 2);
                const float* gsrc = rel + (rtile + rrow)*64 + scol;
                __builtin_amdgcn_global_load_lds(
                    (const __attribute__((address_space(1))) void*)gsrc,
                    (__attribute__((address_space(3))) void*)(wbase + slot*4096 + j*1024 + lane*16),
                    16, 0, 0);
            }
        };
        LOADT(0, 0); LOADT(1, 1); LOADT(2, 2);

        int swz = (fr & 7) << 2;
        #pragma unroll
        for (int t = 0; t < 8; t++) {
            if      (t == 0) asm volatile("s_waitcnt vmcnt(8)"  ::: "memory");
            else if (t == 1) asm volatile("s_waitcnt vmcnt(9)"  ::: "memory");
            else if (t <= 5) asm volatile("s_waitcnt vmcnt(10)" ::: "memory");
            else if (t == 6) asm volatile("s_waitcnt vmcnt(6)"  ::: "memory");
            else             asm volatile("s_waitcnt vmcnt(2)"  ::: "memory");

            const int slot = t % 3;
            const char* sb = wbase + slot*4096 + fr*256;
            f32x4 x[4];
            x[0] = *reinterpret_cast<const f32x4*>(sb + (((fq*8     ) ^ swz) << 2));
            x[1] = *reinterpret_cast<const f32x4*>(sb + (((fq*8 +  4) ^ swz) << 2));
            x[2] = *reinterpret_cast<const f32x4*>(sb + (((fq*8 + 32) ^ swz) << 2));
            x[3] = *reinterpret_cast<const f32x4*>(sb + (((fq*8 + 36) ^ swz) << 2));

            bf16x8 ahi[2], alo[2];
            #pragma unroll
            for (int c = 0; c < 2; c++) {
                #pragma unroll
                for (int p = 0; p < 2; p++) {
                    f32x4 x4 = x[c*2 + p];
                    #pragma unroll
                    for (int e = 0; e < 4; e++) {
                        float xx = x4[e];
                        unsigned int u = __builtin_bit_cast(unsigned int, xx);
                        float hi = __builtin_bit_cast(float, u & 0xffff0000u);
                        float lo = xx - hi;
                        ahi[c][p*4 + e] = (short)(u >> 16);
                        alo[c][p*4 + e] = (short)(__builtin_bit_cast(unsigned int, lo) >> 16);
                    }
                }
            }

            f32x4 acc = {0.f, 0.f, 0.f, 0.f};
            acc = __builtin_amdgcn_mfma_f32_16x16x32_bf16(ahi[0], whi[0], acc, 0, 0, 0);
            acc = __builtin_amdgcn_mfma_f32_16x16x32_bf16(ahi[1], whi[1], acc, 0, 0, 0);
            acc = __builtin_amdgcn_mfma_f32_16x16x32_bf16(alo[0], whi[0], acc, 0, 0, 0);
            acc = __builtin_amdgcn_mfma_f32_16x16x32_bf16(alo[1], whi[1], acc, 0, 0, 0);
            acc = __builtin_amdgcn_mfma_f32_16x16x32_bf16(ahi[0], wlo[0], acc, 0, 0, 0);
            acc = __builtin_amdgcn_mfma_f32_16x16x32_bf16(ahi[1], wlo[1], acc, 0, 0, 0);

            long long rtile = row0 + t*16;
            int b  = (int)(rtile >> 18);
            int q  = (int)((rtile >> 9) & 511);
            int k0 = (int)(rtile & 511);
            ushort4 u4;
            unsigned short* up = reinterpret_cast<unsigned short*>(&u4);
            #pragma unroll
            for (int j = 0; j < 4; j++) {
                float val = acc[j] + brv;
                up[j] = f2bf(__logf(fmaxf(val, 1e-6f)));
            }
            *reinterpret_cast<ushort4*>(
                biasW + ((long long)(b*512 + q)*32 + (k0 >> 4))*256 + fr*16 + fq*4) = u4;

            if (t + 3 < 8) {
                asm volatile("s_waitcnt lgkmcnt(0)" ::: "memory");
                LOADT(t + 3, slot);
            }
        }
    }
}

// ---------------------------------------------------------------- final GEMM (BM=BN=BK=64)
__global__ __launch_bounds__(256) void final_gemm(
    const unsigned short* __restrict__ A, const unsigned short* __restrict__ B,
    const float* __restrict__ bias, float* __restrict__ C)
{
    __shared__ alignas(16) unsigned short As[2][4096];
    __shared__ alignas(16) unsigned short Bs[2][4096];
    int tid = threadIdx.x;
    int wid = tid >> 6, lane = tid & 63;
    int fr = lane & 15, fq = lane >> 4;
    int bm0 = blockIdx.x * 64, bn0 = blockIdx.y * 64;
    int wm = (wid >> 1) * 32, wn = (wid & 1) * 32;

    f32x4 acc[2][2];
    f32x4 z4 = {0.f, 0.f, 0.f, 0.f};
    for (int i = 0; i < 2; i++) for (int j = 0; j < 2; j++) acc[i][j] = z4;

    auto stage = [&](int buf, int kt) {
        #pragma unroll
        for (int i = 0; i < 2; i++) {
            int ci = tid + 256 * i;
            int row = ci >> 3, ch = ci & 7;
            int sch = ch ^ (row & 7);
            const unsigned short* ga = A + (long long)(bm0 + row) * 1024 + kt * 64 + sch * 8;
            __builtin_amdgcn_global_load_lds((const __attribute__((address_space(1))) void*)ga,
                (__attribute__((address_space(3))) void*)(&As[buf][ci * 8]), 16, 0, 0);
            const unsigned short* gb = B + (long long)(bn0 + row) * 1024 + kt * 64 + sch * 8;
            __builtin_amdgcn_global_load_lds((const __attribute__((address_space(1))) void*)gb,
                (__attribute__((address_space(3))) void*)(&Bs[buf][ci * 8]), 16, 0, 0);
        }
    };
    int rx = fr & 7;
    auto compute = [&](int buf) {
        #pragma unroll
        for (int ks = 0; ks < 2; ks++) {
            bf16x8 a[2], b[2];
            #pragma unroll
            for (int fm = 0; fm < 2; fm++)
                a[fm] = *reinterpret_cast<const bf16x8*>(
                    &As[buf][(wm + fm*16 + fr)*64 + ((ks*4 + fq) ^ rx)*8]);
            #pragma unroll
            for (int fn = 0; fn < 2; fn++)
                b[fn] = *reinterpret_cast<const bf16x8*>(
                    &Bs[buf][(wn + fn*16 + fr)*64 + ((ks*4 + fq) ^ rx)*8]);
            #pragma unroll
            for (int fm = 0; fm < 2; fm++)
                #pragma unroll
                for (int fn = 0; fn < 2; fn++)
                    acc[fm][fn] = __builtin_amdgcn_mfma_f32_16x16x32_bf16(a[fm], b[fn], acc[fm][fn], 0, 0, 0);
        }
    };

    stage(0, 0);
    asm volatile("s_waitcnt vmcnt(0)" ::: "memory");
    __syncthreads();
    int cur = 0;
    for (int kt = 0; kt < 15; kt++) {
        stage(cur ^ 1, kt + 1);
        compute(cur);
        asm volatile("s_waitcnt vmcnt(0)" ::: "memory");
        __syncthreads();
        cur ^= 1;
    }
    compute(cur);

    #pragma unroll
    for (int fm = 0; fm < 2; fm++) {
        #pragma unroll
        for (int fn = 0; fn < 2; fn++) {
            int col = bn0 + wn + fn*16 + fr;
            float bv = bias[col];
            f32x4 vacc = acc[fm][fn];
            #pragma unroll
            for (int r = 0; r < 4; r++) {
                int m = bm0 + wm + fm*16 + fq*4 + r;
                C[(long long)m*1024 + col] = vacc[r] + bv;
            }
        }
    }
}

// ---------------------------------------------------------------- attention
__global__ __launch_bounds__(256) void attn_kernel(
    const unsigned short* __restrict__ qh, const unsigned short* __restrict__ kh,
    const unsigned short* __restrict__ vht, const unsigned short* __restrict__ biasW,
    const unsigned char* __restrict__ mask, unsigned short* __restrict__ atted)
{
    __shared__ alignas(16) unsigned short Pl[16][520];
    __shared__ float pmax[4][16];
    __shared__ float psum[4][16];
    int tid = threadIdx.x;
    int wid = tid >> 6, lane = tid & 63;
    int fr = lane & 15, fq = lane >> 4;
    int q0 = blockIdx.x * 16;
    int h = blockIdx.y, b = blockIdx.z;

    bf16x8 aq[2];
    #pragma unroll
    for (int df = 0; df < 2; df++)
        aq[df] = *reinterpret_cast<const bf16x8*>(
            qh + (long long)(b*512 + q0 + fr)*1024 + h*64 + df*32 + fq*8);

    f32x4 s[8];
    #pragma unroll
    for (int kt = 0; kt < 8; kt++) {
        int cb = wid*128 + kt*16;
        f32x4 a4 = {0.f,0.f,0.f,0.f};
        #pragma unroll
        for (int df = 0; df < 2; df++) {
            bf16x8 bk = *reinterpret_cast<const bf16x8*>(
                kh + (long long)(b*512 + cb + fr)*1024 + h*64 + df*32 + fq*8);
            a4 = __builtin_amdgcn_mfma_f32_16x16x32_bf16(aq[df], bk, a4, 0, 0, 0);
        }
        s[kt] = a4;
    }

    // biasW[b][q][kt16][h][kl]: idx = (b*512+q)*8192 + kt16*256 + h*16 + kl
    const unsigned short* bbase = biasW + (long long)(b*512 + q0)*8192 + h*16 + fr;
    #pragma unroll
    for (int kt = 0; kt < 8; kt++) {
        int col = wid*128 + kt*16 + fr;
        bool mk = mask[b*512 + col] != 0;
        #pragma unroll
        for (int r = 0; r < 4; r++) {
            float bias = bf2f(bbase[(long long)(fq*4 + r)*8192 + (wid*8 + kt)*256]);
            float val = s[kt][r] + bias;
            s[kt][r] = mk ? -1e9f : val;
        }
    }

    float rm[4];
    #pragma unroll
    for (int r = 0; r < 4; r++) {
        float m = s[0][r];
        #pragma unroll
        for (int kt = 1; kt < 8; kt++) m = fmaxf(m, s[kt][r]);
        #pragma unroll
        for (int x = 1; x < 16; x <<= 1) m = fmaxf(m, __shfl_xor(m, x, 64));
        rm[r] = m;
    }
    #pragma unroll
    for (int r = 0; r < 4; r++)
        if (fr == r) pmax[wid][fq*4 + r] = rm[r];
    __syncthreads();
    #pragma unroll
    for (int r = 0; r < 4; r++) {
        float m = pmax[0][fq*4 + r];
        m = fmaxf(m, pmax[1][fq*4 + r]);
        m = fmaxf(m, pmax[2][fq*4 + r]);
        m = fmaxf(m, pmax[3][fq*4 + r]);
        rm[r] = m;
    }

    float sum[4] = {0.f, 0.f, 0.f, 0.f};
    #pragma unroll
    for (int kt = 0; kt < 8; kt++) {
        int col = wid*128 + kt*16 + fr;
        #pragma unroll
        for (int r = 0; r < 4; r++) {
            float p = __expf(s[kt][r] - rm[r]);
            sum[r] += p;
            Pl[fq*4 + r][col] = f2bf(p);
        }
    }
    #pragma unroll
    for (int r = 0; r < 4; r++) {
        float sv = sum[r];
        #pragma unroll
        for (int x = 1; x < 16; x <<= 1) sv += __shfl_xor(sv, x, 64);
        sum[r] = sv;
    }
    #pragma unroll
    for (int r = 0; r < 4; r++)
        if (fr == r) psum[wid][fq*4 + r] = sum[r];
    __syncthreads();
    float sumr[4];
    #pragma unroll
    for (int r = 0; r < 4; r++)
        sumr[r] = psum[0][fq*4+r] + psum[1][fq*4+r] + psum[2][fq*4+r] + psum[3][fq*4+r];

    int d0 = wid * 16;
    f32x4 acco = {0.f,0.f,0.f,0.f};
    for (int c = 0; c < 16; c++) {
        bf16x8 pa = *reinterpret_cast<const bf16x8*>(&Pl[fr][c*32 + fq*8]);
        bf16x8 bv = *reinterpret_cast<const bf16x8*>(
            vht + ((long long)(b*16 + h)*64 + d0 + fr)*512 + c*32 + fq*8);
        acco = __builtin_amdgcn_mfma_f32_16x16x32_bf16(pa, bv, acco, 0, 0, 0);
    }
    #pragma unroll
    for (int r = 0; r < 4; r++) {
        float val = acco[r] / sumr[r];
        atted[(long long)(b*512 + q0 + fq*4 + r)*1024 + h*64 + d0 + fr] = f2bf(val);
    }
}

// ---------------------------------------------------------------- launch
extern "C" void kernel_launch(void* const* d_in, const int* in_sizes, int n_in,
                              void* d_out, int out_size, void* d_ws, size_t ws_size,
                              hipStream_t stream)
{
    const float* v    = (const float*)d_in[0];
    const float* k    = (const float*)d_in[1];
    const float* q    = (const float*)d_in[2];
    const unsigned char* mask = (const unsigned char*)d_in[3];
    const float* rel  = (const float*)d_in[4];
    const float* Wv   = (const float*)d_in[5];
    const float* bv   = (const float*)d_in[6];
    const float* Wk   = (const float*)d_in[7];
    const float* bk   = (const float*)d_in[8];
    const float* Wq   = (const float*)d_in[9];
    const float* bq   = (const float*)d_in[10];
    const float* Wr   = (const float*)d_in[11];
    const float* br   = (const float*)d_in[12];
    const float* Wm   = (const float*)d_in[13];
    const float* bm   = (const float*)d_in[14];

    const long long MB = 1 << 20;
    char* W = (char*)d_ws;
    unsigned short* xq    = (unsigned short*)(W + 0*MB);
    unsigned short* xk    = (unsigned short*)(W + 4*MB);
    unsigned short* xv    = (unsigned short*)(W + 8*MB);
    unsigned short* Wqb   = (unsigned short*)(W + 12*MB);
    unsigned short* Wkb   = (unsigned short*)(W + 14*MB);
    unsigned short* Wvb   = (unsigned short*)(W + 16*MB);
    unsigned short* Wmb   = (unsigned short*)(W + 18*MB);
    unsigned short* qhb   = (unsigned short*)(W + 20*MB);
    unsigned short* khb   = (unsigned short*)(W + 24*MB);
    unsigned short* vht   = (unsigned short*)(W + 28*MB);
    unsigned short* atted = (unsigned short*)(W + 32*MB);
    unsigned short* biasW = (unsigned short*)(W + 36*MB);  // 32 MB

    convert_kernel<<<10240, 256, 0, stream>>>(q, k, v, Wq, Wk, Wv, Wm, (unsigned short*)W);

    Gemm3 gp;
    gp.j[0] = { xq, Wqb, bq, (char*)qhb, 2 };
    gp.j[1] = { xk, Wkb, bk, (char*)khb, 1 };
    gp.j[2] = { xv, Wvb, bv, (char*)vht, 3 };
    gemm_rel<<<384 + 2048, 256, 0, stream>>>(gp, rel, Wr, br, biasW);

    attn_kernel<<<dim3(32, 16, 4), 256, 0, stream>>>(qhb, khb, vht, biasW, mask, atted);

    final_gemm<<<dim3(32, 16), 256, 0, stream>>>(atted, Wmb, bm, (float*)d_out);
}